// Round 7
// baseline (272.356 us; speedup 1.0000x reference)
//
#include <hip/hip_runtime.h>
#include <math.h>

#define BB 64
#define CC 1024
#define QQ 256
#define DD 128
#define NEGV (-1.0e30f)

typedef short bf8 __attribute__((ext_vector_type(8)));
typedef short bf4 __attribute__((ext_vector_type(4)));
typedef float f4v __attribute__((ext_vector_type(4)));

__device__ __forceinline__ short f2bf(float f) {
    unsigned u = __builtin_bit_cast(unsigned, f);
    u += 0x7FFFu + ((u >> 16) & 1u);            // RNE
    return (short)(u >> 16);
}
__device__ __forceinline__ float bf2f(short s) {
    unsigned u = ((unsigned)(unsigned short)s) << 16;
    return __builtin_bit_cast(float, u);
}

// ---------------- k0: merged convert + transpose + masked s-vector ----------------
// bid < 1024: xc path (R=1024); else xq path (R=256, rm *= W2).
// XCD-bijective: batch b == bid&7 (mod 8) -> same XCD as consumers.
__global__ __launch_bounds__(256, 4) void k0_all(
        const float* __restrict__ xc, const float* __restrict__ xq,
        const float* __restrict__ W0, const float* __restrict__ W1,
        const float* __restrict__ W2,
        const float* __restrict__ c_mask, const float* __restrict__ q_mask,
        float* __restrict__ s0m, float* __restrict__ s1m,
        short* __restrict__ xc_bf, short* __restrict__ xqw_bf,
        short* __restrict__ xcT_bf, short* __restrict__ xqT_bf) {
    __shared__ float tile[64][129];     // 129-pad: conflict-light column reads
    int bid = blockIdx.x;
    const float *src, *W, *mask;
    float* sm; short *rm, *tr;
    int b, tl, R; bool use2;
    if (bid < 1024) {
        b = ((bid >> 7) << 3) | (bid & 7); tl = (bid >> 3) & 15; R = CC;
        src = xc; W = W0; mask = c_mask; sm = s0m; rm = xc_bf; tr = xcT_bf; use2 = false;
    } else {
        int q = bid - 1024;
        b = ((q >> 5) << 3) | (q & 7); tl = (q >> 3) & 3; R = QQ;
        src = xq; W = W1; mask = q_mask; sm = s1m; rm = xqw_bf; tr = xqT_bf; use2 = true;
    }
    int r0 = tl * 64;
    int t = threadIdx.x;
    int c4 = t & 31, rr = t >> 5;
    float4 wv = ((const float4*)W)[c4];
    float4 sc4 = use2 ? ((const float4*)W2)[c4] : make_float4(1.f, 1.f, 1.f, 1.f);
    const float* sb = src + ((size_t)b * R + r0) * DD;
    #pragma unroll
    for (int p = 0; p < 8; ++p) {
        int row = rr + p * 8;
        float4 g = *(const float4*)&sb[(size_t)row * DD + c4 * 4];
        bf4 o;
        o[0] = f2bf(g.x * sc4.x); o[1] = f2bf(g.y * sc4.y);
        o[2] = f2bf(g.z * sc4.z); o[3] = f2bf(g.w * sc4.w);
        *(bf4*)&rm[((size_t)(b * R + r0 + row)) * DD + c4 * 4] = o;
        float part = g.x * wv.x + g.y * wv.y + g.z * wv.z + g.w * wv.w;
        #pragma unroll
        for (int off = 1; off < 32; off <<= 1) part += __shfl_xor(part, off, 64);
        if ((t & 31) == 0)
            sm[(size_t)b * R + r0 + row] =
                part + NEGV * (1.0f - mask[(size_t)b * R + r0 + row]);
        tile[row][c4 * 4 + 0] = g.x; tile[row][c4 * 4 + 1] = g.y;
        tile[row][c4 * 4 + 2] = g.z; tile[row][c4 * 4 + 3] = g.w;
    }
    __syncthreads();
    // coalesced transpose-out: 8 lanes per d-row write 16 B each (128 B/row)
    int rj = (t & 7) * 8;
    #pragma unroll
    for (int pp = 0; pp < 4; ++pp) {
        int d = pp * 32 + (t >> 3);
        bf8 o;
        #pragma unroll
        for (int j = 0; j < 8; ++j) o[j] = f2bf(tile[rj + j][d]);
        *(bf8*)&tr[((size_t)(b * DD + d)) * R + r0 + rj] = o;
    }
}

// ---------------- kS: S^T[b][q][c] = xqw @ xc^T (fp32 out, no LDS) ----------------
// grid 2048: bid = x + 8*(idx + 32*bh), b = bh*8+x, idx = qt*8+ct.
// Per block: [64 q][128 c], K = 128 d.  Same MFMA chain order as the old
// in-kernel S computation -> bitwise-identical scores.
__global__ __launch_bounds__(256, 4) void kS_gemm(
        const short* __restrict__ xc_bf, const short* __restrict__ xqw_bf,
        float* __restrict__ S0T) {
    int bid = blockIdx.x;
    int idx = (bid >> 3) & 31;
    int b = ((bid >> 8) << 3) | (bid & 7);
    int qt = idx >> 3, ct = idx & 7;
    int t = threadIdx.x, w = t >> 6, l = t & 63;
    int quad = l >> 4, l16 = l & 15;

    const short* ab = &xqw_bf[(size_t)(b * QQ + qt * 64 + w * 16 + l16) * DD + quad * 8];
    bf8 a0 = *(const bf8*)&ab[0];
    bf8 a1 = *(const bf8*)&ab[32];
    bf8 a2 = *(const bf8*)&ab[64];
    bf8 a3 = *(const bf8*)&ab[96];

    const short* bbase = &xc_bf[(size_t)(b * CC + ct * 128 + l16) * DD + quad * 8];
    bf8 bb[2][4];
    #pragma unroll
    for (int ks = 0; ks < 4; ++ks) bb[0][ks] = *(const bf8*)&bbase[ks * 32];

    f4v acc[8];
    #pragma unroll
    for (int nf = 0; nf < 8; ++nf) acc[nf] = (f4v){0.f, 0.f, 0.f, 0.f};

    #pragma unroll
    for (int nf = 0; nf < 8; ++nf) {
        if (nf < 7) {
            const short* nb = bbase + (size_t)(nf + 1) * 16 * DD;
            #pragma unroll
            for (int ks = 0; ks < 4; ++ks) bb[(nf + 1) & 1][ks] = *(const bf8*)&nb[ks * 32];
        }
        const bf8* c = bb[nf & 1];
        acc[nf] = __builtin_amdgcn_mfma_f32_16x16x32_bf16(a0, c[0], acc[nf], 0, 0, 0);
        acc[nf] = __builtin_amdgcn_mfma_f32_16x16x32_bf16(a1, c[1], acc[nf], 0, 0, 0);
        acc[nf] = __builtin_amdgcn_mfma_f32_16x16x32_bf16(a2, c[2], acc[nf], 0, 0, 0);
        acc[nf] = __builtin_amdgcn_mfma_f32_16x16x32_bf16(a3, c[3], acc[nf], 0, 0, 0);
    }

    size_t obase = (size_t)(b * QQ + qt * 64 + w * 16 + quad * 4) * CC + ct * 128 + l16;
    #pragma unroll
    for (int r = 0; r < 4; ++r)
        #pragma unroll
        for (int nf = 0; nf < 8; ++nf)
            S0T[obase + (size_t)r * CC + nf * 16] = acc[r < 4 ? nf : nf][r];   // D: col=c(l16), row=q(quad*4+r)
}

#define SCP 1032   // k1 score row stride (bf16)
#define S2P 264    // k2 score row stride (bf16)
#define XTP 72     // per-wave staged slab stride

// per-wave slab: wave w stages its own 32 d-rows; lane covers rows sr+8p, col c8l*8.
#define K1_LDS2(G, CT)                                                   \
    {                                                                    \
        G[0] = *(const bf8*)&tbase[(CT) * 64];                           \
        G[1] = *(const bf8*)&tbase[(size_t)8 * CC + (CT) * 64];          \
        G[2] = *(const bf8*)&tbase[(size_t)16 * CC + (CT) * 64];         \
        G[3] = *(const bf8*)&tbase[(size_t)24 * CC + (CT) * 64];         \
    }

#define K1_WRS2(G)                                                       \
    {                                                                    \
        *(bf8*)&xct[w][sr][c8l * 8] = G[0];                              \
        *(bf8*)&xct[w][sr + 8][c8l * 8] = G[1];                          \
        *(bf8*)&xct[w][sr + 16][c8l * 8] = G[2];                         \
        *(bf8*)&xct[w][sr + 24][c8l * 8] = G[3];                         \
    }

#define K1_CSTEP(CT)                                                               \
    {                                                                              \
        bf8 a0 = *(const bf8*)&sc[l16][(CT) * 64 + quad * 8];                      \
        bf8 b0 = *(const bf8*)&xct[w][l16][quad * 8];                              \
        acc0 = __builtin_amdgcn_mfma_f32_16x16x32_bf16(a0, b0, acc0, 0, 0, 0);     \
        bf8 b1 = *(const bf8*)&xct[w][16 + l16][quad * 8];                         \
        acc1 = __builtin_amdgcn_mfma_f32_16x16x32_bf16(a0, b1, acc1, 0, 0, 0);     \
        bf8 a1 = *(const bf8*)&sc[l16][(CT) * 64 + 32 + quad * 8];                 \
        bf8 b2 = *(const bf8*)&xct[w][l16][32 + quad * 8];                         \
        acc0 = __builtin_amdgcn_mfma_f32_16x16x32_bf16(a1, b2, acc0, 0, 0, 0);     \
        bf8 b3 = *(const bf8*)&xct[w][16 + l16][32 + quad * 8];                    \
        acc1 = __builtin_amdgcn_mfma_f32_16x16x32_bf16(a1, b3, acc1, 0, 0, 0);     \
    }

// ---------------- k1: col softmax over c, AT[b][d][q] ----------------
// sc filled from precomputed S0T (coalesced) + s0m[c] (s1 cancels over c).
// Phase B: vectorized softmax.  Phase C: per-wave slabs, no barriers.
__global__ __launch_bounds__(256, 3) void k1_colsm(
        const float* __restrict__ S0T, const short* __restrict__ xcT_bf,
        const float* __restrict__ s0m, short* __restrict__ AT) {
    __shared__ __align__(16) short sc[16][SCP];      // 33.0 KB scores [q][c]
    __shared__ __align__(16) short xct[4][32][XTP];  // 18.4 KB per-wave slabs
    __shared__ float invl[16];

    int bid = blockIdx.x;
    int qt = (bid >> 3) & 15;
    int b = ((bid >> 7) << 3) | (bid & 7);   // whole batch on one XCD
    int q0 = qt * 16;
    int t = threadIdx.x, w = t >> 6, l = t & 63;
    int quad = l >> 4, l16 = l & 15;

    // ---- fill sc[q][c] = S0[q][c] + s0m[c] (one coalesced pass) ----
    {
        int fq = t & 15, fseg = t >> 4;
        const float4* srow = (const float4*)(S0T + (size_t)(b * QQ + q0 + fq) * CC + fseg * 64);
        const float4* brow = (const float4*)(s0m + (size_t)b * CC + fseg * 64);
        #pragma unroll
        for (int j = 0; j < 8; ++j) {
            float4 v0 = srow[2 * j], v1 = srow[2 * j + 1];
            float4 m0 = brow[2 * j], m1 = brow[2 * j + 1];
            bf8 o;
            o[0] = f2bf(v0.x + m0.x); o[1] = f2bf(v0.y + m0.y);
            o[2] = f2bf(v0.z + m0.z); o[3] = f2bf(v0.w + m0.w);
            o[4] = f2bf(v1.x + m1.x); o[5] = f2bf(v1.y + m1.y);
            o[6] = f2bf(v1.z + m1.z); o[7] = f2bf(v1.w + m1.w);
            *(bf8*)&sc[fq][fseg * 64 + j * 8] = o;
        }
    }

    // phase-C slab prefetch: tiles 0,1 into regs (land under phase B)
    int c8l = l & 7, sr = l >> 3;
    const short* tbase = &xcT_bf[(size_t)(b * DD + w * 32 + sr) * CC + c8l * 8];
    bf8 gS0[4], gS1[4];
    K1_LDS2(gS0, 0);
    K1_LDS2(gS1, 1);

    __syncthreads();

    // ---- phase B: softmax over c per q (vectorized b128 LDS) ----
    {
        int q = t >> 4, k = t & 15;
        bf8 v[8];
        #pragma unroll
        for (int j = 0; j < 8; ++j) v[j] = *(const bf8*)&sc[q][k * 8 + j * 128];
        float m = -3.0e38f;
        #pragma unroll
        for (int j = 0; j < 8; ++j)
            #pragma unroll
            for (int e = 0; e < 8; ++e) m = fmaxf(m, bf2f(v[j][e]));
        #pragma unroll
        for (int off = 1; off < 16; off <<= 1) m = fmaxf(m, __shfl_xor(m, off, 64));
        float sum = 0.f;
        #pragma unroll
        for (int j = 0; j < 8; ++j) {
            bf8 o;
            #pragma unroll
            for (int e = 0; e < 8; ++e) {
                float ex = __expf(bf2f(v[j][e]) - m);
                sum += ex;
                o[e] = f2bf(ex);
            }
            *(bf8*)&sc[q][k * 8 + j * 128] = o;
        }
        #pragma unroll
        for (int off = 1; off < 16; off <<= 1) sum += __shfl_xor(sum, off, 64);
        if (k == 0) invl[q] = 1.0f / sum;
    }
    __syncthreads();

    // ---- phase C: AT (M=q, N=d, K=c); per-wave slabs, no barriers ----
    f4v acc0 = {0.f, 0.f, 0.f, 0.f}, acc1 = {0.f, 0.f, 0.f, 0.f};
    K1_WRS2(gS0);          // tile0 into slab (landed under softmax)
    K1_LDS2(gS0, 2);       // gS0 <- tile2
    #pragma unroll
    for (int ct = 0; ct < 16; ++ct) {
        K1_CSTEP(ct);
        if (ct < 15) {
            if ((ct & 1) == 0) {
                K1_WRS2(gS1);                       // tile ct+1 (odd -> gS1)
                if (ct + 3 < 16) K1_LDS2(gS1, ct + 3);
            } else {
                K1_WRS2(gS0);                       // tile ct+1 (even -> gS0)
                if (ct + 3 < 16) K1_LDS2(gS0, ct + 3);
            }
        }
    }
    {
        bf4 o0, o1;
        #pragma unroll
        for (int r = 0; r < 4; ++r) {
            float il = invl[quad * 4 + r];
            o0[r] = f2bf(acc0[r] * il);
            o1[r] = f2bf(acc1[r] * il);
        }
        int d0 = w * 32 + l16;
        *(bf4*)&AT[(size_t)(b * DD + d0) * QQ + q0 + quad * 4] = o0;
        *(bf4*)&AT[(size_t)(b * DD + d0 + 16) * QQ + q0 + quad * 4] = o1;
    }
}

// ============================== k2 ==============================
#define K2_SRC(NT) ((NT) < 4 ? (qtb + (size_t)((NT) & 3) * 64) : (atb + (size_t)((NT) - 4) * 64))

#define K2_LDS2(G, NT)                                                   \
    {                                                                    \
        const short* gs_ = K2_SRC(NT);                                   \
        G[0] = *(const bf8*)&gs_[0];                                     \
        G[1] = *(const bf8*)&gs_[(size_t)8 * QQ];                        \
        G[2] = *(const bf8*)&gs_[(size_t)16 * QQ];                       \
        G[3] = *(const bf8*)&gs_[(size_t)24 * QQ];                       \
    }

#define K2_WRS2(G)                                                       \
    {                                                                    \
        *(bf8*)&tT[w][sr][c8l * 8] = G[0];                               \
        *(bf8*)&tT[w][sr + 8][c8l * 8] = G[1];                           \
        *(bf8*)&tT[w][sr + 16][c8l * 8] = G[2];                          \
        *(bf8*)&tT[w][sr + 24][c8l * 8] = G[3];                          \
    }

#define K2_CSTEP(TL)                                                                   \
    {                                                                                  \
        int qoff_ = ((TL) & 3) * 64;                                                   \
        _Pragma("unroll")                                                              \
        for (int ks = 0; ks < 2; ++ks) {                                               \
            bf8 a0 = *(const bf8*)&sc2[l16][qoff_ + ks * 32 + quad * 8];               \
            bf8 a1 = *(const bf8*)&sc2[16 + l16][qoff_ + ks * 32 + quad * 8];          \
            bf8 b0 = *(const bf8*)&tT[w][l16][ks * 32 + quad * 8];                     \
            bf8 b1 = *(const bf8*)&tT[w][16 + l16][ks * 32 + quad * 8];                \
            if ((TL) < 4) {                                                            \
                ac[0][0] = __builtin_amdgcn_mfma_f32_16x16x32_bf16(a0, b0, ac[0][0], 0, 0, 0); \
                ac[0][1] = __builtin_amdgcn_mfma_f32_16x16x32_bf16(a0, b1, ac[0][1], 0, 0, 0); \
                ac[1][0] = __builtin_amdgcn_mfma_f32_16x16x32_bf16(a1, b0, ac[1][0], 0, 0, 0); \
                ac[1][1] = __builtin_amdgcn_mfma_f32_16x16x32_bf16(a1, b1, ac[1][1], 0, 0, 0); \
            } else {                                                                   \
                aq[0][0] = __builtin_amdgcn_mfma_f32_16x16x32_bf16(a0, b0, aq[0][0], 0, 0, 0); \
                aq[0][1] = __builtin_amdgcn_mfma_f32_16x16x32_bf16(a0, b1, aq[0][1], 0, 0, 0); \
                aq[1][0] = __builtin_amdgcn_mfma_f32_16x16x32_bf16(a1, b0, aq[1][0], 0, 0, 0); \
                aq[1][1] = __builtin_amdgcn_mfma_f32_16x16x32_bf16(a1, b1, aq[1][1], 0, 0, 0); \
            }                                                                          \
        }                                                                              \
    }

// ---------------- k2: row softmax over q, c2q / q2c, fused concat ----------------
// sc2 filled from precomputed S0T (+ s1m[q]; s0 cancels over q).
// Phase 3: per-wave slabs, no barriers.  Epilogue: LDS transpose + float4 stores.
__global__ __launch_bounds__(256, 4) void k2_rowsm(
        const float* __restrict__ xc, const float* __restrict__ S0T,
        const short* __restrict__ xqT_bf, const short* __restrict__ AT,
        const float* __restrict__ s1m, float* __restrict__ out) {
    __shared__ __align__(16) short sc2[32][S2P];     // 16.9 KB scores [c][q]
    __shared__ __align__(16) short tT[4][32][XTP];   // 18.4 KB per-wave slabs
    __shared__ float invl2[32];

    int bid = blockIdx.x;
    int cb = (bid >> 3) & 31;
    int b = ((bid >> 8) << 3) | (bid & 7);
    int c0g = cb * 32;
    int t = threadIdx.x, w = t >> 6, l = t & 63;
    int quad = l >> 4, l16 = l & 15;

    // ---- fill sc2[c][q] = S0[q][c0g+c] + s1m[q] (transpose fill) ----
    {
        const float4* srow = (const float4*)(S0T + (size_t)(b * QQ + t) * CC + c0g);
        float s1v = s1m[(size_t)b * QQ + t];
        #pragma unroll
        for (int j = 0; j < 8; ++j) {
            float4 v = srow[j];
            sc2[j * 4 + 0][t] = f2bf(v.x + s1v);
            sc2[j * 4 + 1][t] = f2bf(v.y + s1v);
            sc2[j * 4 + 2][t] = f2bf(v.z + s1v);
            sc2[j * 4 + 3][t] = f2bf(v.w + s1v);
        }
    }

    // phase-3 slab prefetch: tiles 0,1 into regs (land under phase 2)
    int c8l = l & 7, sr = l >> 3;
    const short* qtb = &xqT_bf[(size_t)(b * DD + w * 32 + sr) * QQ + c8l * 8];
    const short* atb = &AT[(size_t)(b * DD + w * 32 + sr) * QQ + c8l * 8];
    bf8 gS0[4], gS1[4];
    K2_LDS2(gS0, 0);
    K2_LDS2(gS1, 1);

    __syncthreads();

    // ---- phase 2: softmax over q per c (vectorized b128 LDS) ----
    {
        int c = t >> 3, k = t & 7;
        bf8 v[4];
        #pragma unroll
        for (int j = 0; j < 4; ++j) v[j] = *(const bf8*)&sc2[c][k * 8 + j * 64];
        float m = -3.0e38f;
        #pragma unroll
        for (int j = 0; j < 4; ++j)
            #pragma unroll
            for (int e = 0; e < 8; ++e) m = fmaxf(m, bf2f(v[j][e]));
        #pragma unroll
        for (int off = 1; off < 8; off <<= 1) m = fmaxf(m, __shfl_xor(m, off, 64));
        float sum = 0.f;
        #pragma unroll
        for (int j = 0; j < 4; ++j) {
            bf8 o;
            #pragma unroll
            for (int e = 0; e < 8; ++e) {
                float ex = __expf(bf2f(v[j][e]) - m);
                sum += ex;
                o[e] = f2bf(ex);
            }
            *(bf8*)&sc2[c][k * 8 + j * 64] = o;
        }
        #pragma unroll
        for (int off = 1; off < 8; off <<= 1) sum += __shfl_xor(sum, off, 64);
        if (k == 0) invl2[c] = 1.0f / sum;
    }
    __syncthreads();

    // ---- phase 3: c2q (tiles 0-3 xqT), q2c (tiles 4-7 AT); per-wave slabs ----
    f4v ac[2][2], aq[2][2];
    f4v zz = {0.f, 0.f, 0.f, 0.f};
    #pragma unroll
    for (int i = 0; i < 2; ++i)
        #pragma unroll
        for (int j = 0; j < 2; ++j) { ac[i][j] = zz; aq[i][j] = zz; }
    K2_WRS2(gS0);          // tile0 (landed under softmax)
    K2_LDS2(gS0, 2);
    #pragma unroll
    for (int tl = 0; tl < 8; ++tl) {
        K2_CSTEP(tl);
        if (tl < 7) {
            if ((tl & 1) == 0) {
                K2_WRS2(gS1);
                if (tl + 3 < 8) K2_LDS2(gS1, tl + 3);
            } else {
                K2_WRS2(gS0);
                if (tl + 3 < 8) K2_LDS2(gS0, tl + 3);
            }
        }
    }

    // ---- epilogue: LDS transpose then float4 stores ----
    __syncthreads();       // all waves done reading sc2/tT
    float (*c2l)[132] = (float(*)[132])sc2;   // 32x132 f32 = 16.9 KB (fits sc2)
    float (*q2l)[132] = (float(*)[132])tT;    // fits tT (18.4 KB)
    #pragma unroll
    for (int cf = 0; cf < 2; ++cf)
        #pragma unroll
        for (int df = 0; df < 2; ++df)
            #pragma unroll
            for (int r = 0; r < 4; ++r) {
                int cl = cf * 16 + quad * 4 + r;
                int d = w * 32 + df * 16 + l16;
                c2l[cl][d] = ac[cf][df][r];
                q2l[cl][d] = aq[cf][df][r];
            }
    __syncthreads();
    {
        int cl = t >> 3, j4 = (t & 7) * 4;
        float il = invl2[cl];
        const float* xrow = xc + (size_t)(b * CC + c0g + cl) * DD;
        float* orow = out + (size_t)(b * CC + c0g + cl) * (4 * DD);
        #pragma unroll
        for (int ps = 0; ps < 4; ++ps) {
            int d = ps * 32 + j4;
            float4 xv = *(const float4*)&xrow[d];
            float4 cv = *(const float4*)&c2l[cl][d];
            float4 qv = *(const float4*)&q2l[cl][d];
            cv.x *= il; cv.y *= il; cv.z *= il; cv.w *= il;
            qv.x *= il; qv.y *= il; qv.z *= il; qv.w *= il;
            *(float4*)&orow[d] = xv;
            *(float4*)&orow[DD + d] = cv;
            float4 m2 = make_float4(xv.x * cv.x, xv.y * cv.y, xv.z * cv.z, xv.w * cv.w);
            *(float4*)&orow[2 * DD + d] = m2;
            float4 m3 = make_float4(xv.x * qv.x, xv.y * qv.y, xv.z * qv.z, xv.w * qv.w);
            *(float4*)&orow[3 * DD + d] = m3;
        }
    }
}

extern "C" void kernel_launch(void* const* d_in, const int* in_sizes, int n_in,
                              void* d_out, int out_size, void* d_ws, size_t ws_size,
                              hipStream_t stream) {
    const float* x_cont = (const float*)d_in[0];
    const float* x_ques = (const float*)d_in[1];
    const float* c_mask = (const float*)d_in[2];
    const float* q_mask = (const float*)d_in[3];
    const float* W0     = (const float*)d_in[4];
    const float* W1     = (const float*)d_in[5];
    const float* W2     = (const float*)d_in[6];
    // bias cancels in both softmaxes.
    float* out = (float*)d_out;

    char* ws = (char*)d_ws;
    float* s0m    = (float*)ws;  ws += (size_t)BB * CC * 4;
    float* s1m    = (float*)ws;  ws += (size_t)BB * QQ * 4;
    short* xc_bf  = (short*)ws;  ws += (size_t)BB * CC * DD * 2;
    short* xqw_bf = (short*)ws;  ws += (size_t)BB * QQ * DD * 2;
    short* xcT_bf = (short*)ws;  ws += (size_t)BB * CC * DD * 2;
    short* xqT_bf = (short*)ws;  ws += (size_t)BB * QQ * DD * 2;
    short* AT     = (short*)ws;  ws += (size_t)BB * DD * QQ * 2;
    float* S0T    = (float*)ws;  // B*Q*C f32 = 67 MB

    k0_all<<<BB * 16 + BB * 4, 256, 0, stream>>>(x_cont, x_ques, W0, W1, W2,
                                                 c_mask, q_mask, s0m, s1m,
                                                 xc_bf, xqw_bf, xcT_bf, xqT_bf);
    kS_gemm<<<BB * 32, 256, 0, stream>>>(xc_bf, xqw_bf, S0T);
    k1_colsm<<<BB * 16, 256, 0, stream>>>(S0T, xcT_bf, s0m, AT);
    k2_rowsm<<<BB * 32, 256, 0, stream>>>(x_cont, S0T, xqT_bf, AT, s1m, out);
}

// Round 8
// 259.035 us; speedup vs baseline: 1.0514x; 1.0514x over previous
//
#include <hip/hip_runtime.h>
#include <math.h>

#define BB 64
#define CC 1024
#define QQ 256
#define DD 128
#define NEGV (-1.0e30f)

typedef short bf8 __attribute__((ext_vector_type(8)));
typedef short bf4 __attribute__((ext_vector_type(4)));
typedef float f4v __attribute__((ext_vector_type(4)));

__device__ __forceinline__ short f2bf(float f) {
    unsigned u = __builtin_bit_cast(unsigned, f);
    u += 0x7FFFu + ((u >> 16) & 1u);            // RNE
    return (short)(u >> 16);
}
__device__ __forceinline__ float bf2f(short s) {
    unsigned u = ((unsigned)(unsigned short)s) << 16;
    return __builtin_bit_cast(float, u);
}

// ---------------- k0: merged convert + transpose + masked s-vector ----------------
// bid < 1024: xc path (R=1024); else xq path (R=256, rm *= W2).
// XCD-bijective: batch b == bid&7 (mod 8) -> same XCD as k1/k2 consumers.
__global__ __launch_bounds__(256, 4) void k0_all(
        const float* __restrict__ xc, const float* __restrict__ xq,
        const float* __restrict__ W0, const float* __restrict__ W1,
        const float* __restrict__ W2,
        const float* __restrict__ c_mask, const float* __restrict__ q_mask,
        float* __restrict__ s0m, float* __restrict__ s1m,
        short* __restrict__ xc_bf, short* __restrict__ xqw_bf,
        short* __restrict__ xcT_bf, short* __restrict__ xqT_bf) {
    __shared__ float tile[64][129];     // 129-pad: conflict-light column reads
    int bid = blockIdx.x;
    const float *src, *W, *mask;
    float* sm; short *rm, *tr;
    int b, tl, R; bool use2;
    if (bid < 1024) {
        b = ((bid >> 7) << 3) | (bid & 7); tl = (bid >> 3) & 15; R = CC;
        src = xc; W = W0; mask = c_mask; sm = s0m; rm = xc_bf; tr = xcT_bf; use2 = false;
    } else {
        int q = bid - 1024;
        b = ((q >> 5) << 3) | (q & 7); tl = (q >> 3) & 3; R = QQ;
        src = xq; W = W1; mask = q_mask; sm = s1m; rm = xqw_bf; tr = xqT_bf; use2 = true;
    }
    int r0 = tl * 64;
    int t = threadIdx.x;
    int c4 = t & 31, rr = t >> 5;
    float4 wv = ((const float4*)W)[c4];
    float4 sc4 = use2 ? ((const float4*)W2)[c4] : make_float4(1.f, 1.f, 1.f, 1.f);
    const float* sb = src + ((size_t)b * R + r0) * DD;
    #pragma unroll
    for (int p = 0; p < 8; ++p) {
        int row = rr + p * 8;
        float4 g = *(const float4*)&sb[(size_t)row * DD + c4 * 4];
        bf4 o;
        o[0] = f2bf(g.x * sc4.x); o[1] = f2bf(g.y * sc4.y);
        o[2] = f2bf(g.z * sc4.z); o[3] = f2bf(g.w * sc4.w);
        *(bf4*)&rm[((size_t)(b * R + r0 + row)) * DD + c4 * 4] = o;
        float part = g.x * wv.x + g.y * wv.y + g.z * wv.z + g.w * wv.w;
        #pragma unroll
        for (int off = 1; off < 32; off <<= 1) part += __shfl_xor(part, off, 64);
        if ((t & 31) == 0)
            sm[(size_t)b * R + r0 + row] =
                part + NEGV * (1.0f - mask[(size_t)b * R + r0 + row]);
        tile[row][c4 * 4 + 0] = g.x; tile[row][c4 * 4 + 1] = g.y;
        tile[row][c4 * 4 + 2] = g.z; tile[row][c4 * 4 + 3] = g.w;
    }
    __syncthreads();
    // coalesced transpose-out: 8 lanes per d-row write 16 B each (128 B/row)
    int rj = (t & 7) * 8;
    #pragma unroll
    for (int pp = 0; pp < 4; ++pp) {
        int d = pp * 32 + (t >> 3);
        bf8 o;
        #pragma unroll
        for (int j = 0; j < 8; ++j) o[j] = f2bf(tile[rj + j][d]);
        *(bf8*)&tr[((size_t)(b * DD + d)) * R + r0 + rj] = o;
    }
}

#define SCP 1032   // k1 score row stride (bf16)
#define S2P 264    // k2 score row stride (bf16)
#define XTP 72     // per-wave staged slab stride

// ============================== k1 ==============================
#define K1_LDA(G, S, CT)                                                 \
    {                                                                    \
        const short* ar_ = abase + (size_t)(CT) * 64 * DD;               \
        G[0] = *(const bf8*)&ar_[0];  G[1] = *(const bf8*)&ar_[32];      \
        G[2] = *(const bf8*)&ar_[64]; G[3] = *(const bf8*)&ar_[96];      \
        S = *(const f4v*)&s0base[(CT) * 64];                             \
    }

#define K1_STEPA(G, S, CT)                                                            \
    {                                                                                 \
        f4v acc = {0.f, 0.f, 0.f, 0.f};                                               \
        acc = __builtin_amdgcn_mfma_f32_16x16x32_bf16(G[0], bq[0], acc, 0, 0, 0);     \
        acc = __builtin_amdgcn_mfma_f32_16x16x32_bf16(G[1], bq[1], acc, 0, 0, 0);     \
        acc = __builtin_amdgcn_mfma_f32_16x16x32_bf16(G[2], bq[2], acc, 0, 0, 0);     \
        acc = __builtin_amdgcn_mfma_f32_16x16x32_bf16(G[3], bq[3], acc, 0, 0, 0);     \
        bf4 ov;                                                                       \
        ov[0] = f2bf(acc[0] + S[0]); ov[1] = f2bf(acc[1] + S[1]);                     \
        ov[2] = f2bf(acc[2] + S[2]); ov[3] = f2bf(acc[3] + S[3]);                     \
        *(bf4*)&sc[l16][(CT) * 64 + w * 16 + quad * 4] = ov;                          \
        if ((CT) + 4 < 16) K1_LDA(G, S, (CT) + 4);                                    \
    }

// per-wave slab: wave w stages its own 32 d-rows; lane covers rows sr+8p, col c8l*8.
#define K1_LDS2(G, CT)                                                   \
    {                                                                    \
        G[0] = *(const bf8*)&tbase[(CT) * 64];                           \
        G[1] = *(const bf8*)&tbase[(size_t)8 * CC + (CT) * 64];          \
        G[2] = *(const bf8*)&tbase[(size_t)16 * CC + (CT) * 64];         \
        G[3] = *(const bf8*)&tbase[(size_t)24 * CC + (CT) * 64];         \
    }

#define K1_WRS2(G)                                                       \
    {                                                                    \
        *(bf8*)&xct[w][sr][c8l * 8] = G[0];                              \
        *(bf8*)&xct[w][sr + 8][c8l * 8] = G[1];                          \
        *(bf8*)&xct[w][sr + 16][c8l * 8] = G[2];                         \
        *(bf8*)&xct[w][sr + 24][c8l * 8] = G[3];                         \
    }

#define K1_CSTEP(CT)                                                               \
    {                                                                              \
        bf8 a0 = *(const bf8*)&sc[l16][(CT) * 64 + quad * 8];                      \
        bf8 b0 = *(const bf8*)&xct[w][l16][quad * 8];                              \
        acc0 = __builtin_amdgcn_mfma_f32_16x16x32_bf16(a0, b0, acc0, 0, 0, 0);     \
        bf8 b1 = *(const bf8*)&xct[w][16 + l16][quad * 8];                         \
        acc1 = __builtin_amdgcn_mfma_f32_16x16x32_bf16(a0, b1, acc1, 0, 0, 0);     \
        bf8 a1 = *(const bf8*)&sc[l16][(CT) * 64 + 32 + quad * 8];                 \
        bf8 b2 = *(const bf8*)&xct[w][l16][32 + quad * 8];                         \
        acc0 = __builtin_amdgcn_mfma_f32_16x16x32_bf16(a1, b2, acc0, 0, 0, 0);     \
        bf8 b3 = *(const bf8*)&xct[w][16 + l16][32 + quad * 8];                    \
        acc1 = __builtin_amdgcn_mfma_f32_16x16x32_bf16(a1, b3, acc1, 0, 0, 0);     \
    }

#define K1_ROT(G, CT)                                                    \
    {                                                                    \
        K1_WRS2(G);                                                      \
        if ((CT) + 4 < 16) K1_LDS2(G, (CT) + 4);                         \
    }

// ---------------- k1: col softmax over c, AT[b][d][q] ----------------
// Phase A: 4-deep reg rolling prefetch, reg-resident B.  Phase B: vectorized
// b128 softmax.  Phase C: per-wave private slabs, 3-deep rotation, no barriers.
__global__ __launch_bounds__(256, 3) void k1_colsm(
        const short* __restrict__ xc_bf, const short* __restrict__ xcT_bf,
        const short* __restrict__ xqw_bf, const float* __restrict__ s0m,
        short* __restrict__ AT) {
    __shared__ __align__(16) short sc[16][SCP];      // 33.0 KB scores [q][c]
    __shared__ __align__(16) short xct[4][32][XTP];  // 18.4 KB per-wave slabs
    __shared__ float invl[16];

    int bid = blockIdx.x;
    int qt = (bid >> 3) & 15;
    int b = ((bid >> 7) << 3) | (bid & 7);   // whole batch on one XCD
    int q0 = qt * 16;
    int t = threadIdx.x, w = t >> 6, l = t & 63;
    int quad = l >> 4, l16 = l & 15;

    // block-constant B-op: 16 xqw rows, fragment-resident
    bf8 bq[4];
    {
        const short* qp = &xqw_bf[(size_t)(b * QQ + q0 + l16) * DD + quad * 8];
        #pragma unroll
        for (int ks = 0; ks < 4; ++ks) bq[ks] = *(const bf8*)&qp[ks * 32];
    }

    // ---- phase A: S[c][q] (M=c, N=q, K=d), barrier-free, 4-deep prefetch ----
    const short* abase = &xc_bf[(size_t)(b * CC + w * 16 + l16) * DD + quad * 8];
    const float* s0base = &s0m[b * CC + w * 16 + quad * 4];
    bf8 gA[4], gB[4], gC[4], gD[4];
    f4v sA, sB, sC, sD;
    K1_LDA(gA, sA, 0); K1_LDA(gB, sB, 1); K1_LDA(gC, sC, 2); K1_LDA(gD, sD, 3);
    #pragma unroll
    for (int c4t = 0; c4t < 16; c4t += 4) {
        K1_STEPA(gA, sA, c4t + 0);
        K1_STEPA(gB, sB, c4t + 1);
        K1_STEPA(gC, sC, c4t + 2);
        K1_STEPA(gD, sD, c4t + 3);
    }

    // phase-C slab prefetch: tiles 0,1,2 into regs (land under phase B)
    int c8l = l & 7, sr = l >> 3;
    const short* tbase = &xcT_bf[(size_t)(b * DD + w * 32 + sr) * CC + c8l * 8];
    bf8 gS0[4], gS1[4], gS2[4];
    K1_LDS2(gS0, 0);
    K1_LDS2(gS1, 1);
    K1_LDS2(gS2, 2);

    __syncthreads();

    // ---- phase B: softmax over c per q (vectorized b128 LDS) ----
    {
        int q = t >> 4, k = t & 15;
        bf8 v[8];
        #pragma unroll
        for (int j = 0; j < 8; ++j) v[j] = *(const bf8*)&sc[q][k * 8 + j * 128];
        float m = -3.0e38f;
        #pragma unroll
        for (int j = 0; j < 8; ++j)
            #pragma unroll
            for (int e = 0; e < 8; ++e) m = fmaxf(m, bf2f(v[j][e]));
        #pragma unroll
        for (int off = 1; off < 16; off <<= 1) m = fmaxf(m, __shfl_xor(m, off, 64));
        float sum = 0.f;
        #pragma unroll
        for (int j = 0; j < 8; ++j) {
            bf8 o;
            #pragma unroll
            for (int e = 0; e < 8; ++e) {
                float ex = __expf(bf2f(v[j][e]) - m);
                sum += ex;
                o[e] = f2bf(ex);
            }
            *(bf8*)&sc[q][k * 8 + j * 128] = o;
        }
        #pragma unroll
        for (int off = 1; off < 16; off <<= 1) sum += __shfl_xor(sum, off, 64);
        if (k == 0) invl[q] = 1.0f / sum;
    }
    __syncthreads();

    // ---- phase C: AT (M=q, N=d, K=c); per-wave slabs, 3-deep, no barriers ----
    f4v acc0 = {0.f, 0.f, 0.f, 0.f}, acc1 = {0.f, 0.f, 0.f, 0.f};
    K1_WRS2(gS0);          // tile0 into slab (landed under softmax)
    K1_LDS2(gS0, 3);       // gS0 <- tile3
    #pragma unroll
    for (int ct = 0; ct < 16; ++ct) {
        K1_CSTEP(ct);
        if (ct < 15) {
            int nb = (ct + 1) % 3;
            if (nb == 0)      K1_ROT(gS0, ct)
            else if (nb == 1) K1_ROT(gS1, ct)
            else              K1_ROT(gS2, ct)
        }
    }
    {
        bf4 o0, o1;
        #pragma unroll
        for (int r = 0; r < 4; ++r) {
            float il = invl[quad * 4 + r];
            o0[r] = f2bf(acc0[r] * il);
            o1[r] = f2bf(acc1[r] * il);
        }
        int d0 = w * 32 + l16;
        *(bf4*)&AT[(size_t)(b * DD + d0) * QQ + q0 + quad * 4] = o0;
        *(bf4*)&AT[(size_t)(b * DD + d0 + 16) * QQ + q0 + quad * 4] = o1;
    }
}

// ============================== k2 ==============================
#define K2_LDA(G, CT)                                                    \
    {                                                                    \
        const short* ar_ = abase + (size_t)(CT) * 64 * DD;               \
        G[0] = *(const bf8*)&ar_[0];  G[1] = *(const bf8*)&ar_[32];      \
        G[2] = *(const bf8*)&ar_[64]; G[3] = *(const bf8*)&ar_[96];      \
    }

#define K2_STEP1(G, SV, QT)                                                           \
    {                                                                                 \
        f4v acc0 = {0.f, 0.f, 0.f, 0.f}, acc1 = {0.f, 0.f, 0.f, 0.f};                 \
        acc0 = __builtin_amdgcn_mfma_f32_16x16x32_bf16(G[0], bc0[0], acc0, 0, 0, 0);  \
        acc1 = __builtin_amdgcn_mfma_f32_16x16x32_bf16(G[0], bc1[0], acc1, 0, 0, 0);  \
        acc0 = __builtin_amdgcn_mfma_f32_16x16x32_bf16(G[1], bc0[1], acc0, 0, 0, 0);  \
        acc1 = __builtin_amdgcn_mfma_f32_16x16x32_bf16(G[1], bc1[1], acc1, 0, 0, 0);  \
        acc0 = __builtin_amdgcn_mfma_f32_16x16x32_bf16(G[2], bc0[2], acc0, 0, 0, 0);  \
        acc1 = __builtin_amdgcn_mfma_f32_16x16x32_bf16(G[2], bc1[2], acc1, 0, 0, 0);  \
        acc0 = __builtin_amdgcn_mfma_f32_16x16x32_bf16(G[3], bc0[3], acc0, 0, 0, 0);  \
        acc1 = __builtin_amdgcn_mfma_f32_16x16x32_bf16(G[3], bc1[3], acc1, 0, 0, 0);  \
        int qbase_ = (QT) * 64 + w * 16 + quad * 4;                                   \
        bf4 o0, o1;                                                                   \
        o0[0] = f2bf(acc0[0] + SV[0]); o0[1] = f2bf(acc0[1] + SV[1]);                 \
        o0[2] = f2bf(acc0[2] + SV[2]); o0[3] = f2bf(acc0[3] + SV[3]);                 \
        o1[0] = f2bf(acc1[0] + SV[0]); o1[1] = f2bf(acc1[1] + SV[1]);                 \
        o1[2] = f2bf(acc1[2] + SV[2]); o1[3] = f2bf(acc1[3] + SV[3]);                 \
        *(bf4*)&sc2[l16][qbase_] = o0;                                                \
        *(bf4*)&sc2[16 + l16][qbase_] = o1;                                           \
    }

#define K2_SRC(NT) ((NT) < 4 ? (qtb + (size_t)((NT) & 3) * 64) : (atb + (size_t)((NT) - 4) * 64))

#define K2_LDS2(G, NT)                                                   \
    {                                                                    \
        const short* gs_ = K2_SRC(NT);                                   \
        G[0] = *(const bf8*)&gs_[0];                                     \
        G[1] = *(const bf8*)&gs_[(size_t)8 * QQ];                        \
        G[2] = *(const bf8*)&gs_[(size_t)16 * QQ];                       \
        G[3] = *(const bf8*)&gs_[(size_t)24 * QQ];                       \
    }

#define K2_WRS2(G)                                                       \
    {                                                                    \
        *(bf8*)&tT[w][sr][c8l * 8] = G[0];                               \
        *(bf8*)&tT[w][sr + 8][c8l * 8] = G[1];                           \
        *(bf8*)&tT[w][sr + 16][c8l * 8] = G[2];                          \
        *(bf8*)&tT[w][sr + 24][c8l * 8] = G[3];                          \
    }

#define K2_CSTEP(TL)                                                                   \
    {                                                                                  \
        int qoff_ = ((TL) & 3) * 64;                                                   \
        _Pragma("unroll")                                                              \
        for (int ks = 0; ks < 2; ++ks) {                                               \
            bf8 a0 = *(const bf8*)&sc2[l16][qoff_ + ks * 32 + quad * 8];               \
            bf8 a1 = *(const bf8*)&sc2[16 + l16][qoff_ + ks * 32 + quad * 8];          \
            bf8 b0 = *(const bf8*)&tT[w][l16][ks * 32 + quad * 8];                     \
            bf8 b1 = *(const bf8*)&tT[w][16 + l16][ks * 32 + quad * 8];                \
            if ((TL) < 4) {                                                            \
                ac[0][0] = __builtin_amdgcn_mfma_f32_16x16x32_bf16(a0, b0, ac[0][0], 0, 0, 0); \
                ac[0][1] = __builtin_amdgcn_mfma_f32_16x16x32_bf16(a0, b1, ac[0][1], 0, 0, 0); \
                ac[1][0] = __builtin_amdgcn_mfma_f32_16x16x32_bf16(a1, b0, ac[1][0], 0, 0, 0); \
                ac[1][1] = __builtin_amdgcn_mfma_f32_16x16x32_bf16(a1, b1, ac[1][1], 0, 0, 0); \
            } else {                                                                   \
                aq[0][0] = __builtin_amdgcn_mfma_f32_16x16x32_bf16(a0, b0, aq[0][0], 0, 0, 0); \
                aq[0][1] = __builtin_amdgcn_mfma_f32_16x16x32_bf16(a0, b1, aq[0][1], 0, 0, 0); \
                aq[1][0] = __builtin_amdgcn_mfma_f32_16x16x32_bf16(a1, b0, aq[1][0], 0, 0, 0); \
                aq[1][1] = __builtin_amdgcn_mfma_f32_16x16x32_bf16(a1, b1, aq[1][1], 0, 0, 0); \
            }                                                                          \
        }                                                                              \
    }

#define K2_ROT(G, TL)                                                    \
    {                                                                    \
        K2_WRS2(G);                                                      \
        if ((TL) + 4 < 8) K2_LDS2(G, (TL) + 4);                          \
    }

// ---------------- k2: row softmax over q, c2q / q2c, fused concat ----------------
// Phase 3: per-wave slabs, 3-deep, no barriers.  Epilogue: LDS transpose + float4.
__global__ __launch_bounds__(256, 4) void k2_rowsm(
        const float* __restrict__ xc, const short* __restrict__ xc_bf,
        const short* __restrict__ xqw_bf, const short* __restrict__ xqT_bf,
        const short* __restrict__ AT, const float* __restrict__ s1m,
        float* __restrict__ out) {
    __shared__ __align__(16) short sc2[32][S2P];     // 16.9 KB scores [c][q]
    __shared__ __align__(16) short tT[4][32][XTP];   // 18.4 KB per-wave slabs
    __shared__ float invl2[32];

    int bid = blockIdx.x;
    int cb = (bid >> 3) & 31;
    int b = ((bid >> 8) << 3) | (bid & 7);
    int c0g = cb * 32;
    int t = threadIdx.x, w = t >> 6, l = t & 63;
    int quad = l >> 4, l16 = l & 15;

    // block-constant B-op: 32 xc rows, fragment-resident
    bf8 bc0[4], bc1[4];
    {
        const short* p0 = &xc_bf[(size_t)(b * CC + c0g + l16) * DD + quad * 8];
        const short* p1 = p0 + 16 * DD;
        #pragma unroll
        for (int ks = 0; ks < 4; ++ks) {
            bc0[ks] = *(const bf8*)&p0[ks * 32];
            bc1[ks] = *(const bf8*)&p1[ks * 32];
        }
    }

    // ---- phase 1: S^T (M=q, N=c, K=d), barrier-free, 2-buffer rolling ----
    const short* abase = &xqw_bf[(size_t)(b * QQ + w * 16 + l16) * DD + quad * 8];
    const float* s1base = &s1m[b * QQ + w * 16 + quad * 4];
    f4v sv0 = *(const f4v*)&s1base[0];
    f4v sv1 = *(const f4v*)&s1base[64];
    f4v sv2 = *(const f4v*)&s1base[128];
    f4v sv3 = *(const f4v*)&s1base[192];
    bf8 gA[4], gB[4];
    K2_LDA(gA, 0); K2_LDA(gB, 1);
    K2_STEP1(gA, sv0, 0); K2_LDA(gA, 2);
    K2_STEP1(gB, sv1, 1); K2_LDA(gB, 3);
    K2_STEP1(gA, sv2, 2);
    K2_STEP1(gB, sv3, 3);

    // phase-3 slab prefetch: tiles 0,1,2 into regs (land under phase 2)
    int c8l = l & 7, sr = l >> 3;
    const short* qtb = &xqT_bf[(size_t)(b * DD + w * 32 + sr) * QQ + c8l * 8];
    const short* atb = &AT[(size_t)(b * DD + w * 32 + sr) * QQ + c8l * 8];
    bf8 gS0[4], gS1[4], gS2[4];
    K2_LDS2(gS0, 0);
    K2_LDS2(gS1, 1);
    K2_LDS2(gS2, 2);

    __syncthreads();

    // ---- phase 2: softmax over q per c (vectorized b128 LDS) ----
    {
        int c = t >> 3, k = t & 7;
        bf8 v[4];
        #pragma unroll
        for (int j = 0; j < 4; ++j) v[j] = *(const bf8*)&sc2[c][k * 8 + j * 64];
        float m = -3.0e38f;
        #pragma unroll
        for (int j = 0; j < 4; ++j)
            #pragma unroll
            for (int e = 0; e < 8; ++e) m = fmaxf(m, bf2f(v[j][e]));
        #pragma unroll
        for (int off = 1; off < 8; off <<= 1) m = fmaxf(m, __shfl_xor(m, off, 64));
        float sum = 0.f;
        #pragma unroll
        for (int j = 0; j < 4; ++j) {
            bf8 o;
            #pragma unroll
            for (int e = 0; e < 8; ++e) {
                float ex = __expf(bf2f(v[j][e]) - m);
                sum += ex;
                o[e] = f2bf(ex);
            }
            *(bf8*)&sc2[c][k * 8 + j * 64] = o;
        }
        #pragma unroll
        for (int off = 1; off < 8; off <<= 1) sum += __shfl_xor(sum, off, 64);
        if (k == 0) invl2[c] = 1.0f / sum;
    }
    __syncthreads();

    // ---- phase 3: c2q (tiles 0-3 xqT), q2c (tiles 4-7 AT); per-wave slabs ----
    f4v ac[2][2], aq[2][2];
    f4v zz = {0.f, 0.f, 0.f, 0.f};
    #pragma unroll
    for (int i = 0; i < 2; ++i)
        #pragma unroll
        for (int j = 0; j < 2; ++j) { ac[i][j] = zz; aq[i][j] = zz; }
    K2_WRS2(gS0);          // tile0 (landed under softmax)
    K2_LDS2(gS0, 3);       // gS0 <- tile3
    #pragma unroll
    for (int tl = 0; tl < 8; ++tl) {
        K2_CSTEP(tl);
        if (tl < 7) {
            int nb = (tl + 1) % 3;
            if (nb == 0)      K2_ROT(gS0, tl)
            else if (nb == 1) K2_ROT(gS1, tl)
            else              K2_ROT(gS2, tl)
        }
    }

    // ---- epilogue: LDS transpose then float4 stores ----
    __syncthreads();       // all waves done reading sc2/tT
    float (*c2l)[132] = (float(*)[132])sc2;   // 32x132 f32 = 16.9 KB (fits sc2)
    float (*q2l)[132] = (float(*)[132])tT;    // fits tT (18.4 KB)
    #pragma unroll
    for (int cf = 0; cf < 2; ++cf)
        #pragma unroll
        for (int df = 0; df < 2; ++df)
            #pragma unroll
            for (int r = 0; r < 4; ++r) {
                int cl = cf * 16 + quad * 4 + r;
                int d = w * 32 + df * 16 + l16;
                c2l[cl][d] = ac[cf][df][r];
                q2l[cl][d] = aq[cf][df][r];
            }
    __syncthreads();
    {
        int cl = t >> 3, j4 = (t & 7) * 4;
        float il = invl2[cl];
        const float* xrow = xc + (size_t)(b * CC + c0g + cl) * DD;
        float* orow = out + (size_t)(b * CC + c0g + cl) * (4 * DD);
        #pragma unroll
        for (int ps = 0; ps < 4; ++ps) {
            int d = ps * 32 + j4;
            float4 xv = *(const float4*)&xrow[d];
            float4 cv = *(const float4*)&c2l[cl][d];
            float4 qv = *(const float4*)&q2l[cl][d];
            cv.x *= il; cv.y *= il; cv.z *= il; cv.w *= il;
            qv.x *= il; qv.y *= il; qv.z *= il; qv.w *= il;
            *(float4*)&orow[d] = xv;
            *(float4*)&orow[DD + d] = cv;
            float4 m2 = make_float4(xv.x * cv.x, xv.y * cv.y, xv.z * cv.z, xv.w * cv.w);
            *(float4*)&orow[2 * DD + d] = m2;
            float4 m3 = make_float4(xv.x * qv.x, xv.y * qv.y, xv.z * qv.z, xv.w * qv.w);
            *(float4*)&orow[3 * DD + d] = m3;
        }
    }
}

extern "C" void kernel_launch(void* const* d_in, const int* in_sizes, int n_in,
                              void* d_out, int out_size, void* d_ws, size_t ws_size,
                              hipStream_t stream) {
    const float* x_cont = (const float*)d_in[0];
    const float* x_ques = (const float*)d_in[1];
    const float* c_mask = (const float*)d_in[2];
    const float* q_mask = (const float*)d_in[3];
    const float* W0     = (const float*)d_in[4];
    const float* W1     = (const float*)d_in[5];
    const float* W2     = (const float*)d_in[6];
    // bias cancels in both softmaxes.
    float* out = (float*)d_out;

    char* ws = (char*)d_ws;
    float* s0m    = (float*)ws;  ws += (size_t)BB * CC * 4;
    float* s1m    = (float*)ws;  ws += (size_t)BB * QQ * 4;
    short* xc_bf  = (short*)ws;  ws += (size_t)BB * CC * DD * 2;
    short* xqw_bf = (short*)ws;  ws += (size_t)BB * QQ * DD * 2;
    short* xcT_bf = (short*)ws;  ws += (size_t)BB * CC * DD * 2;
    short* xqT_bf = (short*)ws;  ws += (size_t)BB * QQ * DD * 2;
    short* AT     = (short*)ws;  // B*D*Q

    k0_all<<<BB * 16 + BB * 4, 256, 0, stream>>>(x_cont, x_ques, W0, W1, W2,
                                                 c_mask, q_mask, s0m, s1m,
                                                 xc_bf, xqw_bf, xcT_bf, xqT_bf);
    k1_colsm<<<BB * 16, 256, 0, stream>>>(xc_bf, xcT_bf, xqw_bf, s0m, AT);
    k2_rowsm<<<BB * 32, 256, 0, stream>>>(x_cont, xc_bf, xqw_bf, xqT_bf, AT, s1m, out);
}

// Round 9
// 252.903 us; speedup vs baseline: 1.0769x; 1.0242x over previous
//
#include <hip/hip_runtime.h>
#include <math.h>

#define BB 64
#define CC 1024
#define QQ 256
#define DD 128
#define NEGV (-1.0e30f)

typedef short bf8 __attribute__((ext_vector_type(8)));
typedef short bf4 __attribute__((ext_vector_type(4)));
typedef float f4v __attribute__((ext_vector_type(4)));

__device__ __forceinline__ short f2bf(float f) {
    unsigned u = __builtin_bit_cast(unsigned, f);
    u += 0x7FFFu + ((u >> 16) & 1u);            // RNE
    return (short)(u >> 16);
}
__device__ __forceinline__ float bf2f(short s) {
    unsigned u = ((unsigned)(unsigned short)s) << 16;
    return __builtin_bit_cast(float, u);
}

// ---------------- k0: merged convert + transpose + masked s-vector ----------------
// bf16 LDS tile (16.9 KB) -> 5 blocks/CU; grid 1280 = exactly one round.
// bid < 1024: xc path (R=1024); else xq path (R=256, rm *= W2).
// XCD-bijective: batch b == bid&7 (mod 8) -> same XCD as k1/k2 consumers.
__global__ __launch_bounds__(256, 5) void k0_all(
        const float* __restrict__ xc, const float* __restrict__ xq,
        const float* __restrict__ W0, const float* __restrict__ W1,
        const float* __restrict__ W2,
        const float* __restrict__ c_mask, const float* __restrict__ q_mask,
        float* __restrict__ s0m, float* __restrict__ s1m,
        short* __restrict__ xc_bf, short* __restrict__ xqw_bf,
        short* __restrict__ xcT_bf, short* __restrict__ xqT_bf) {
    __shared__ short tile[64][132];     // bf16 tile: 16.9 KB
    int bid = blockIdx.x;
    const float *src, *W, *mask;
    float* sm; short *rm, *tr;
    int b, tl, R; bool use2;
    if (bid < 1024) {
        b = ((bid >> 7) << 3) | (bid & 7); tl = (bid >> 3) & 15; R = CC;
        src = xc; W = W0; mask = c_mask; sm = s0m; rm = xc_bf; tr = xcT_bf; use2 = false;
    } else {
        int q = bid - 1024;
        b = ((q >> 5) << 3) | (q & 7); tl = (q >> 3) & 3; R = QQ;
        src = xq; W = W1; mask = q_mask; sm = s1m; rm = xqw_bf; tr = xqT_bf; use2 = true;
    }
    int r0 = tl * 64;
    int t = threadIdx.x;
    int c4 = t & 31, rr = t >> 5;
    float4 wv = ((const float4*)W)[c4];
    float4 sc4 = use2 ? ((const float4*)W2)[c4] : make_float4(1.f, 1.f, 1.f, 1.f);
    const float* sb = src + ((size_t)b * R + r0) * DD;
    #pragma unroll
    for (int p = 0; p < 8; ++p) {
        int row = rr + p * 8;
        float4 g = *(const float4*)&sb[(size_t)row * DD + c4 * 4];
        bf4 o;
        o[0] = f2bf(g.x * sc4.x); o[1] = f2bf(g.y * sc4.y);
        o[2] = f2bf(g.z * sc4.z); o[3] = f2bf(g.w * sc4.w);
        *(bf4*)&rm[((size_t)(b * R + r0 + row)) * DD + c4 * 4] = o;
        float part = g.x * wv.x + g.y * wv.y + g.z * wv.z + g.w * wv.w;
        #pragma unroll
        for (int off = 1; off < 32; off <<= 1) part += __shfl_xor(part, off, 64);
        if ((t & 31) == 0)
            sm[(size_t)b * R + r0 + row] =
                part + NEGV * (1.0f - mask[(size_t)b * R + r0 + row]);
        bf4 u;      // unscaled bf16 for the transposed copy (same bits as before)
        u[0] = f2bf(g.x); u[1] = f2bf(g.y); u[2] = f2bf(g.z); u[3] = f2bf(g.w);
        *(bf4*)&tile[row][c4 * 4] = u;
    }
    __syncthreads();
    // coalesced transpose-out: 8 lanes per d-row write 16 B each (128 B/row)
    int rj = (t & 7) * 8;
    #pragma unroll
    for (int pp = 0; pp < 4; ++pp) {
        int d = pp * 32 + (t >> 3);
        bf8 o;
        #pragma unroll
        for (int j = 0; j < 8; ++j) o[j] = tile[rj + j][d];
        *(bf8*)&tr[((size_t)(b * DD + d)) * R + r0 + rj] = o;
    }
}

#define SCP 1032   // k1 score row stride (bf16)
#define S2P 264    // k2 score row stride (bf16)
#define XTP 72     // per-wave staged slab stride

// ============================== k1 (512 threads, 8 waves) ==============================
// Phase A: 8 iters (128 c-rows each: 8 waves x 16 rows), 3-deep rolling prefetch.
#define K1_LDA(G, S, CT)                                                 \
    {                                                                    \
        const short* ar_ = abase + (size_t)(CT) * 128 * DD;              \
        G[0] = *(const bf8*)&ar_[0];  G[1] = *(const bf8*)&ar_[32];      \
        G[2] = *(const bf8*)&ar_[64]; G[3] = *(const bf8*)&ar_[96];      \
        S = *(const f4v*)&s0base[(CT) * 128];                            \
    }

#define K1_STEPA(G, S, CT)                                                            \
    {                                                                                 \
        f4v acc = {0.f, 0.f, 0.f, 0.f};                                               \
        acc = __builtin_amdgcn_mfma_f32_16x16x32_bf16(G[0], bq[0], acc, 0, 0, 0);     \
        acc = __builtin_amdgcn_mfma_f32_16x16x32_bf16(G[1], bq[1], acc, 0, 0, 0);     \
        acc = __builtin_amdgcn_mfma_f32_16x16x32_bf16(G[2], bq[2], acc, 0, 0, 0);     \
        acc = __builtin_amdgcn_mfma_f32_16x16x32_bf16(G[3], bq[3], acc, 0, 0, 0);     \
        bf4 ov;                                                                       \
        ov[0] = f2bf(acc[0] + S[0]); ov[1] = f2bf(acc[1] + S[1]);                     \
        ov[2] = f2bf(acc[2] + S[2]); ov[3] = f2bf(acc[3] + S[3]);                     \
        *(bf4*)&sc[l16][(CT) * 128 + w * 16 + quad * 4] = ov;                         \
        if ((CT) + 3 < 8) K1_LDA(G, S, (CT) + 3);                                     \
    }

// per-wave slab: wave w stages its own 16 d-rows (w*16..+15); lane covers
// rows sr, sr+8 (sr=l>>3), col c8l*8 — 2x16 B per tile.
#define K1_LDS2(G, CT)                                                   \
    {                                                                    \
        G[0] = *(const bf8*)&tbase[(CT) * 64];                           \
        G[1] = *(const bf8*)&tbase[(size_t)8 * CC + (CT) * 64];          \
    }

#define K1_WRS2(G)                                                       \
    {                                                                    \
        *(bf8*)&xct[w][sr][c8l * 8] = G[0];                              \
        *(bf8*)&xct[w][sr + 8][c8l * 8] = G[1];                          \
    }

#define K1_CSTEP(CT)                                                               \
    {                                                                              \
        bf8 a0 = *(const bf8*)&sc[l16][(CT) * 64 + quad * 8];                      \
        bf8 b0 = *(const bf8*)&xct[w][l16][quad * 8];                              \
        acc0 = __builtin_amdgcn_mfma_f32_16x16x32_bf16(a0, b0, acc0, 0, 0, 0);     \
        bf8 a1 = *(const bf8*)&sc[l16][(CT) * 64 + 32 + quad * 8];                 \
        bf8 b1 = *(const bf8*)&xct[w][l16][32 + quad * 8];                         \
        acc0 = __builtin_amdgcn_mfma_f32_16x16x32_bf16(a1, b1, acc0, 0, 0, 0);     \
    }

#define K1_ROT(G, CT)                                                    \
    {                                                                    \
        K1_WRS2(G);                                                      \
        if ((CT) + 4 < 16) K1_LDS2(G, (CT) + 4);                         \
    }

// ---------------- k1: col softmax over c, AT[b][d][q] ----------------
// 512-thread blocks: 2 blocks/CU (16 waves/CU), 1024 blocks = 2 clean rounds.
__global__ __launch_bounds__(512, 4) void k1_colsm(
        const short* __restrict__ xc_bf, const short* __restrict__ xcT_bf,
        const short* __restrict__ xqw_bf, const float* __restrict__ s0m,
        short* __restrict__ AT) {
    __shared__ __align__(16) short sc[16][SCP];      // 33.0 KB scores [q][c]
    __shared__ __align__(16) short xct[8][16][XTP];  // 18.4 KB per-wave slabs
    __shared__ float invl[16];

    int bid = blockIdx.x;
    int qt = (bid >> 3) & 15;
    int b = ((bid >> 7) << 3) | (bid & 7);   // whole batch on one XCD
    int q0 = qt * 16;
    int t = threadIdx.x, w = t >> 6, l = t & 63;
    int quad = l >> 4, l16 = l & 15;

    // block-constant B-op: 16 xqw rows, fragment-resident (same in all waves)
    bf8 bq[4];
    {
        const short* qp = &xqw_bf[(size_t)(b * QQ + q0 + l16) * DD + quad * 8];
        #pragma unroll
        for (int ks = 0; ks < 4; ++ks) bq[ks] = *(const bf8*)&qp[ks * 32];
    }

    // ---- phase A: S[c][q] (M=c, N=q, K=d), 8 iters, 3-deep prefetch ----
    const short* abase = &xc_bf[(size_t)(b * CC + w * 16 + l16) * DD + quad * 8];
    const float* s0base = &s0m[b * CC + w * 16 + quad * 4];
    bf8 gA[4], gB[4], gC[4];
    f4v sA, sB, sC;
    K1_LDA(gA, sA, 0); K1_LDA(gB, sB, 1); K1_LDA(gC, sC, 2);
    K1_STEPA(gA, sA, 0);
    K1_STEPA(gB, sB, 1);
    K1_STEPA(gC, sC, 2);
    K1_STEPA(gA, sA, 3);
    K1_STEPA(gB, sB, 4);
    K1_STEPA(gC, sC, 5);
    K1_STEPA(gA, sA, 6);
    K1_STEPA(gB, sB, 7);

    // phase-C slab prefetch: tiles 0,1,2 into regs (land under phase B)
    int c8l = l & 7, sr = l >> 3;
    const short* tbase = &xcT_bf[(size_t)(b * DD + w * 16 + sr) * CC + c8l * 8];
    bf8 gS0[2], gS1[2], gS2[2];
    K1_LDS2(gS0, 0);
    K1_LDS2(gS1, 1);
    K1_LDS2(gS2, 2);

    __syncthreads();

    // ---- phase B: softmax over c per q (32 lanes per q-row, b128 vectorized) ----
    {
        int q = t >> 5, k = t & 31;
        bf8 v[4];
        #pragma unroll
        for (int j = 0; j < 4; ++j) v[j] = *(const bf8*)&sc[q][k * 8 + j * 256];
        float m = -3.0e38f;
        #pragma unroll
        for (int j = 0; j < 4; ++j)
            #pragma unroll
            for (int e = 0; e < 8; ++e) m = fmaxf(m, bf2f(v[j][e]));
        #pragma unroll
        for (int off = 1; off < 32; off <<= 1) m = fmaxf(m, __shfl_xor(m, off, 64));
        float sum = 0.f;
        #pragma unroll
        for (int j = 0; j < 4; ++j) {
            bf8 o;
            #pragma unroll
            for (int e = 0; e < 8; ++e) {
                float ex = __expf(bf2f(v[j][e]) - m);
                sum += ex;
                o[e] = f2bf(ex);
            }
            *(bf8*)&sc[q][k * 8 + j * 256] = o;
        }
        #pragma unroll
        for (int off = 1; off < 32; off <<= 1) sum += __shfl_xor(sum, off, 64);
        if (k == 0) invl[q] = 1.0f / sum;
    }
    __syncthreads();

    // ---- phase C: AT (M=q, N=d, K=c); per-wave 16-d slabs, 3-deep, no barriers ----
    f4v acc0 = {0.f, 0.f, 0.f, 0.f};
    K1_WRS2(gS0);          // tile0 into slab (landed under softmax)
    K1_LDS2(gS0, 3);       // gS0 <- tile3
    #pragma unroll
    for (int ct = 0; ct < 16; ++ct) {
        K1_CSTEP(ct);
        if (ct < 15) {
            int nb = (ct + 1) % 3;
            if (nb == 0)      K1_ROT(gS0, ct)
            else if (nb == 1) K1_ROT(gS1, ct)
            else              K1_ROT(gS2, ct)
        }
    }
    {
        bf4 o0;
        #pragma unroll
        for (int r = 0; r < 4; ++r) o0[r] = f2bf(acc0[r] * invl[quad * 4 + r]);
        int d0 = w * 16 + l16;
        *(bf4*)&AT[(size_t)(b * DD + d0) * QQ + q0 + quad * 4] = o0;
    }
}

// ============================== k2 ==============================
#define K2_LDA(G, CT)                                                    \
    {                                                                    \
        const short* ar_ = abase + (size_t)(CT) * 64 * DD;               \
        G[0] = *(const bf8*)&ar_[0];  G[1] = *(const bf8*)&ar_[32];      \
        G[2] = *(const bf8*)&ar_[64]; G[3] = *(const bf8*)&ar_[96];      \
    }

#define K2_STEP1(G, SV, QT)                                                           \
    {                                                                                 \
        f4v acc0 = {0.f, 0.f, 0.f, 0.f}, acc1 = {0.f, 0.f, 0.f, 0.f};                 \
        acc0 = __builtin_amdgcn_mfma_f32_16x16x32_bf16(G[0], bc0[0], acc0, 0, 0, 0);  \
        acc1 = __builtin_amdgcn_mfma_f32_16x16x32_bf16(G[0], bc1[0], acc1, 0, 0, 0);  \
        acc0 = __builtin_amdgcn_mfma_f32_16x16x32_bf16(G[1], bc0[1], acc0, 0, 0, 0);  \
        acc1 = __builtin_amdgcn_mfma_f32_16x16x32_bf16(G[1], bc1[1], acc1, 0, 0, 0);  \
        acc0 = __builtin_amdgcn_mfma_f32_16x16x32_bf16(G[2], bc0[2], acc0, 0, 0, 0);  \
        acc1 = __builtin_amdgcn_mfma_f32_16x16x32_bf16(G[2], bc1[2], acc1, 0, 0, 0);  \
        acc0 = __builtin_amdgcn_mfma_f32_16x16x32_bf16(G[3], bc0[3], acc0, 0, 0, 0);  \
        acc1 = __builtin_amdgcn_mfma_f32_16x16x32_bf16(G[3], bc1[3], acc1, 0, 0, 0);  \
        int qbase_ = (QT) * 64 + w * 16 + quad * 4;                                   \
        bf4 o0, o1;                                                                   \
        o0[0] = f2bf(acc0[0] + SV[0]); o0[1] = f2bf(acc0[1] + SV[1]);                 \
        o0[2] = f2bf(acc0[2] + SV[2]); o0[3] = f2bf(acc0[3] + SV[3]);                 \
        o1[0] = f2bf(acc1[0] + SV[0]); o1[1] = f2bf(acc1[1] + SV[1]);                 \
        o1[2] = f2bf(acc1[2] + SV[2]); o1[3] = f2bf(acc1[3] + SV[3]);                 \
        *(bf4*)&sc2[l16][qbase_] = o0;                                                \
        *(bf4*)&sc2[16 + l16][qbase_] = o1;                                           \
    }

#define K2_SRC(NT) ((NT) < 4 ? (qtb + (size_t)((NT) & 3) * 64) : (atb + (size_t)((NT) - 4) * 64))

#define K2_LDS2(G, NT)                                                   \
    {                                                                    \
        const short* gs_ = K2_SRC(NT);                                   \
        G[0] = *(const bf8*)&gs_[0];                                     \
        G[1] = *(const bf8*)&gs_[(size_t)8 * QQ];                        \
        G[2] = *(const bf8*)&gs_[(size_t)16 * QQ];                       \
        G[3] = *(const bf8*)&gs_[(size_t)24 * QQ];                       \
    }

#define K2_WRS2(G)                                                       \
    {                                                                    \
        *(bf8*)&tT[w][sr][c8l * 8] = G[0];                               \
        *(bf8*)&tT[w][sr + 8][c8l * 8] = G[1];                           \
        *(bf8*)&tT[w][sr + 16][c8l * 8] = G[2];                          \
        *(bf8*)&tT[w][sr + 24][c8l * 8] = G[3];                          \
    }

#define K2_CSTEP(TL)                                                                   \
    {                                                                                  \
        int qoff_ = ((TL) & 3) * 64;                                                   \
        _Pragma("unroll")                                                              \
        for (int ks = 0; ks < 2; ++ks) {                                               \
            bf8 a0 = *(const bf8*)&sc2[l16][qoff_ + ks * 32 + quad * 8];               \
            bf8 a1 = *(const bf8*)&sc2[16 + l16][qoff_ + ks * 32 + quad * 8];          \
            bf8 b0 = *(const bf8*)&tT[w][l16][ks * 32 + quad * 8];                     \
            bf8 b1 = *(const bf8*)&tT[w][16 + l16][ks * 32 + quad * 8];                \
            if ((TL) < 4) {                                                            \
                ac[0][0] = __builtin_amdgcn_mfma_f32_16x16x32_bf16(a0, b0, ac[0][0], 0, 0, 0); \
                ac[0][1] = __builtin_amdgcn_mfma_f32_16x16x32_bf16(a0, b1, ac[0][1], 0, 0, 0); \
                ac[1][0] = __builtin_amdgcn_mfma_f32_16x16x32_bf16(a1, b0, ac[1][0], 0, 0, 0); \
                ac[1][1] = __builtin_amdgcn_mfma_f32_16x16x32_bf16(a1, b1, ac[1][1], 0, 0, 0); \
            } else {                                                                   \
                aq[0][0] = __builtin_amdgcn_mfma_f32_16x16x32_bf16(a0, b0, aq[0][0], 0, 0, 0); \
                aq[0][1] = __builtin_amdgcn_mfma_f32_16x16x32_bf16(a0, b1, aq[0][1], 0, 0, 0); \
                aq[1][0] = __builtin_amdgcn_mfma_f32_16x16x32_bf16(a1, b0, aq[1][0], 0, 0, 0); \
                aq[1][1] = __builtin_amdgcn_mfma_f32_16x16x32_bf16(a1, b1, aq[1][1], 0, 0, 0); \
            }                                                                          \
        }                                                                              \
    }

#define K2_ROT(G, TL)                                                    \
    {                                                                    \
        K2_WRS2(G);                                                      \
        if ((TL) + 4 < 8) K2_LDS2(G, (TL) + 4);                          \
    }

// ---------------- k2: row softmax over q, c2q / q2c, fused concat ----------------
// (unchanged from R8 best)
__global__ __launch_bounds__(256, 4) void k2_rowsm(
        const float* __restrict__ xc, const short* __restrict__ xc_bf,
        const short* __restrict__ xqw_bf, const short* __restrict__ xqT_bf,
        const short* __restrict__ AT, const float* __restrict__ s1m,
        float* __restrict__ out) {
    __shared__ __align__(16) short sc2[32][S2P];     // 16.9 KB scores [c][q]
    __shared__ __align__(16) short tT[4][32][XTP];   // 18.4 KB per-wave slabs
    __shared__ float invl2[32];

    int bid = blockIdx.x;
    int cb = (bid >> 3) & 31;
    int b = ((bid >> 8) << 3) | (bid & 7);
    int c0g = cb * 32;
    int t = threadIdx.x, w = t >> 6, l = t & 63;
    int quad = l >> 4, l16 = l & 15;

    // block-constant B-op: 32 xc rows, fragment-resident
    bf8 bc0[4], bc1[4];
    {
        const short* p0 = &xc_bf[(size_t)(b * CC + c0g + l16) * DD + quad * 8];
        const short* p1 = p0 + 16 * DD;
        #pragma unroll
        for (int ks = 0; ks < 4; ++ks) {
            bc0[ks] = *(const bf8*)&p0[ks * 32];
            bc1[ks] = *(const bf8*)&p1[ks * 32];
        }
    }

    // ---- phase 1: S^T (M=q, N=c, K=d), barrier-free, 2-buffer rolling ----
    const short* abase = &xqw_bf[(size_t)(b * QQ + w * 16 + l16) * DD + quad * 8];
    const float* s1base = &s1m[b * QQ + w * 16 + quad * 4];
    f4v sv0 = *(const f4v*)&s1base[0];
    f4v sv1 = *(const f4v*)&s1base[64];
    f4v sv2 = *(const f4v*)&s1base[128];
    f4v sv3 = *(const f4v*)&s1base[192];
    bf8 gA[4], gB[4];
    K2_LDA(gA, 0); K2_LDA(gB, 1);
    K2_STEP1(gA, sv0, 0); K2_LDA(gA, 2);
    K2_STEP1(gB, sv1, 1); K2_LDA(gB, 3);
    K2_STEP1(gA, sv2, 2);
    K2_STEP1(gB, sv3, 3);

    // phase-3 slab prefetch: tiles 0,1,2 into regs (land under phase 2)
    int c8l = l & 7, sr = l >> 3;
    const short* qtb = &xqT_bf[(size_t)(b * DD + w * 32 + sr) * QQ + c8l * 8];
    const short* atb = &AT[(size_t)(b * DD + w * 32 + sr) * QQ + c8l * 8];
    bf8 gS0[4], gS1[4], gS2[4];
    K2_LDS2(gS0, 0);
    K2_LDS2(gS1, 1);
    K2_LDS2(gS2, 2);

    __syncthreads();

    // ---- phase 2: softmax over q per c (vectorized b128 LDS) ----
    {
        int c = t >> 3, k = t & 7;
        bf8 v[4];
        #pragma unroll
        for (int j = 0; j < 4; ++j) v[j] = *(const bf8*)&sc2[c][k * 8 + j * 64];
        float m = -3.0e38f;
        #pragma unroll
        for (int j = 0; j < 4; ++j)
            #pragma unroll
            for (int e = 0; e < 8; ++e) m = fmaxf(m, bf2f(v[j][e]));
        #pragma unroll
        for (int off = 1; off < 8; off <<= 1) m = fmaxf(m, __shfl_xor(m, off, 64));
        float sum = 0.f;
        #pragma unroll
        for (int j = 0; j < 4; ++j) {
            bf8 o;
            #pragma unroll
            for (int e = 0; e < 8; ++e) {
                float ex = __expf(bf2f(v[j][e]) - m);
                sum += ex;
                o[e] = f2bf(ex);
            }
            *(bf8*)&sc2[c][k * 8 + j * 64] = o;
        }
        #pragma unroll
        for (int off = 1; off < 8; off <<= 1) sum += __shfl_xor(sum, off, 64);
        if (k == 0) invl2[c] = 1.0f / sum;
    }
    __syncthreads();

    // ---- phase 3: c2q (tiles 0-3 xqT), q2c (tiles 4-7 AT); per-wave slabs ----
    f4v ac[2][2], aq[2][2];
    f4v zz = {0.f, 0.f, 0.f, 0.f};
    #pragma unroll
    for (int i = 0; i < 2; ++i)
        #pragma unroll
        for (int j = 0; j < 2; ++j) { ac[i][j] = zz; aq[i][j] = zz; }
    K2_WRS2(gS0);          // tile0 (landed under softmax)
    K2_LDS2(gS0, 3);       // gS0 <- tile3
    #pragma unroll
    for (int tl = 0; tl < 8; ++tl) {
        K2_CSTEP(tl);
        if (tl < 7) {
            int nb = (tl + 1) % 3;
            if (nb == 0)      K2_ROT(gS0, tl)
            else if (nb == 1) K2_ROT(gS1, tl)
            else              K2_ROT(gS2, tl)
        }
    }

    // ---- epilogue: LDS transpose then float4 stores ----
    __syncthreads();       // all waves done reading sc2/tT
    float (*c2l)[132] = (float(*)[132])sc2;   // 32x132 f32 = 16.9 KB (fits sc2)
    float (*q2l)[132] = (float(*)[132])tT;    // fits tT (18.4 KB)
    #pragma unroll
    for (int cf = 0; cf < 2; ++cf)
        #pragma unroll
        for (int df = 0; df < 2; ++df)
            #pragma unroll
            for (int r = 0; r < 4; ++r) {
                int cl = cf * 16 + quad * 4 + r;
                int d = w * 32 + df * 16 + l16;
                c2l[cl][d] = ac[cf][df][r];
                q2l[cl][d] = aq[cf][df][r];
            }
    __syncthreads();
    {
        int cl = t >> 3, j4 = (t & 7) * 4;
        float il = invl2[cl];
        const float* xrow = xc + (size_t)(b * CC + c0g + cl) * DD;
        float* orow = out + (size_t)(b * CC + c0g + cl) * (4 * DD);
        #pragma unroll
        for (int ps = 0; ps < 4; ++ps) {
            int d = ps * 32 + j4;
            float4 xv = *(const float4*)&xrow[d];
            float4 cv = *(const float4*)&c2l[cl][d];
            float4 qv = *(const float4*)&q2l[cl][d];
            cv.x *= il; cv.y *= il; cv.z *= il; cv.w *= il;
            qv.x *= il; qv.y *= il; qv.z *= il; qv.w *= il;
            *(float4*)&orow[d] = xv;
            *(float4*)&orow[DD + d] = cv;
            float4 m2 = make_float4(xv.x * cv.x, xv.y * cv.y, xv.z * cv.z, xv.w * cv.w);
            *(float4*)&orow[2 * DD + d] = m2;
            float4 m3 = make_float4(xv.x * qv.x, xv.y * qv.y, xv.z * qv.z, xv.w * qv.w);
            *(float4*)&orow[3 * DD + d] = m3;
        }
    }
}

extern "C" void kernel_launch(void* const* d_in, const int* in_sizes, int n_in,
                              void* d_out, int out_size, void* d_ws, size_t ws_size,
                              hipStream_t stream) {
    const float* x_cont = (const float*)d_in[0];
    const float* x_ques = (const float*)d_in[1];
    const float* c_mask = (const float*)d_in[2];
    const float* q_mask = (const float*)d_in[3];
    const float* W0     = (const float*)d_in[4];
    const float* W1     = (const float*)d_in[5];
    const float* W2     = (const float*)d_in[6];
    // bias cancels in both softmaxes.
    float* out = (float*)d_out;

    char* ws = (char*)d_ws;
    float* s0m    = (float*)ws;  ws += (size_t)BB * CC * 4;
    float* s1m    = (float*)ws;  ws += (size_t)BB * QQ * 4;
    short* xc_bf  = (short*)ws;  ws += (size_t)BB * CC * DD * 2;
    short* xqw_bf = (short*)ws;  ws += (size_t)BB * QQ * DD * 2;
    short* xcT_bf = (short*)ws;  ws += (size_t)BB * CC * DD * 2;
    short* xqT_bf = (short*)ws;  ws += (size_t)BB * QQ * DD * 2;
    short* AT     = (short*)ws;  // B*D*Q

    k0_all<<<BB * 16 + BB * 4, 256, 0, stream>>>(x_cont, x_ques, W0, W1, W2,
                                                 c_mask, q_mask, s0m, s1m,
                                                 xc_bf, xqw_bf, xcT_bf, xqT_bf);
    k1_colsm<<<BB * 16, 512, 0, stream>>>(xc_bf, xcT_bf, xqw_bf, s0m, AT);
    k2_rowsm<<<BB * 32, 256, 0, stream>>>(x_cont, xc_bf, xqw_bf, xqT_bf, AT, s1m, out);
}